// Round 21
// baseline (1142.971 us; speedup 1.0000x reference)
//
#include <hip/hip_runtime.h>
#include <hip/hip_bf16.h>
#include <cstdint>
#include <cstddef>

typedef __bf16 bf16_t;
typedef __bf16 bf16x8 __attribute__((ext_vector_type(8)));
typedef float f32x4 __attribute__((ext_vector_type(4)));

#define GLB_AS(p) ((__attribute__((address_space(1))) void*)(void*)(p))
#define LDS_AS(p) ((__attribute__((address_space(3))) void*)(p))

// ---------------- helpers ----------------
__device__ __forceinline__ float wave_red_sum(float v) {
#pragma unroll
  for (int o = 1; o < 64; o <<= 1) v += __shfl_xor(v, o, 64);
  return v;
}

__device__ __forceinline__ float gelu_tanh(float v) {
  float c = 0.7978845608028654f * (v + 0.044715f * v * v * v);
  return 0.5f * v * (1.0f + tanhf(c));
}

__device__ __forceinline__ f32x4 mfma16(f32x4 a, f32x4 b, f32x4 c) {
  return __builtin_amdgcn_mfma_f32_16x16x32_bf16(
      __builtin_bit_cast(bf16x8, a), __builtin_bit_cast(bf16x8, b), c, 0, 0, 0);
}

// swizzle for 128B-row LDS tiles: XOR row bits (byte bits 7-9) into slot bits 4-6.
__device__ __forceinline__ int swz(int off) { return off ^ ((off >> 3) & 0x70); }
// swizzle for 64B-row LDS tiles.
__device__ __forceinline__ int swz64(int off) { return off ^ ((off >> 3) & 0x30); }

#define PHASE_WAIT()                                    \
  asm volatile("s_waitcnt lgkmcnt(0)" ::: "memory");    \
  __builtin_amdgcn_sched_barrier(0)

#define LGKM_WAIT(N)                                          \
  asm volatile("s_waitcnt lgkmcnt(" #N ")" ::: "memory");     \
  __builtin_amdgcn_sched_barrier(0)

// ---------------- fused embedding + layernorm (layer-0 ln1) ----------------
__global__ __launch_bounds__(256) void embed_ln_k(const int* __restrict__ idx,
                                                  const float* __restrict__ wte,
                                                  const float* __restrict__ wpe,
                                                  const float* __restrict__ g,
                                                  const float* __restrict__ b,
                                                  float* __restrict__ x,
                                                  bf16_t* __restrict__ out) {
  const int m = blockIdx.x;
  const int tid = threadIdx.x;
  const int tok = idx[m];
  const int t = m & 1023;
  float v[3];
#pragma unroll
  for (int i = 0; i < 3; ++i) {
    const int d = tid + i * 256;
    v[i] = wte[(size_t)tok * 768 + d] + wpe[(size_t)t * 768 + d];
    x[(size_t)m * 768 + d] = v[i];
  }
  float s = v[0] + v[1] + v[2];
  float q = v[0] * v[0] + v[1] * v[1] + v[2] * v[2];
  s = wave_red_sum(s);
  q = wave_red_sum(q);
  __shared__ float sm[8];
  const int wave = tid >> 6, lane = tid & 63;
  if (lane == 0) { sm[wave] = s; sm[4 + wave] = q; }
  __syncthreads();
  s = sm[0] + sm[1] + sm[2] + sm[3];
  q = sm[4] + sm[5] + sm[6] + sm[7];
  const float mu = s * (1.0f / 768.0f);
  const float var = q * (1.0f / 768.0f) - mu * mu;
  const float rs = rsqrtf(var + 1e-5f);
  bf16_t* orow = out + (size_t)m * 768;
#pragma unroll
  for (int i = 0; i < 3; ++i) {
    const int d = tid + i * 256;
    orow[d] = (bf16_t)((v[i] - mu) * rs * g[d] + b[d]);
  }
}

// ---------------- layernorm row -> bf16 ----------------
__global__ __launch_bounds__(256) void ln_k(const float* __restrict__ x,
                                            const float* __restrict__ g,
                                            const float* __restrict__ b,
                                            bf16_t* __restrict__ out) {
  const int row = blockIdx.x;
  const int tid = threadIdx.x;
  const float* xr = x + (size_t)row * 768;
  float v0 = xr[tid], v1 = xr[tid + 256], v2 = xr[tid + 512];
  float s = v0 + v1 + v2;
  float q = v0 * v0 + v1 * v1 + v2 * v2;
  s = wave_red_sum(s);
  q = wave_red_sum(q);
  __shared__ float sm[8];
  const int wave = tid >> 6, lane = tid & 63;
  if (lane == 0) { sm[wave] = s; sm[4 + wave] = q; }
  __syncthreads();
  s = sm[0] + sm[1] + sm[2] + sm[3];
  q = sm[4] + sm[5] + sm[6] + sm[7];
  const float mu = s * (1.0f / 768.0f);
  const float var = q * (1.0f / 768.0f) - mu * mu;
  const float rs = rsqrtf(var + 1e-5f);
  bf16_t* orow = out + (size_t)row * 768;
#pragma unroll
  for (int i = 0; i < 3; ++i) {
    const int d = tid + i * 256;
    const float v = (i == 0 ? v0 : (i == 1 ? v1 : v2));
    orow[d] = (bf16_t)((v - mu) * rs * g[d] + b[d]);
  }
}

// ---------------- all weight transposes in ONE dispatch ----------------
struct TJob { const float* W; bf16_t* WT; int K, N, Npad, blk0, nbx; };
struct TJobs { TJob j[9]; };

__global__ __launch_bounds__(256) void transp_all(TJobs jobs) {
  __shared__ float tile[32][33];
  const int bidx = blockIdx.x;
  int ji = 0;
#pragma unroll
  for (int u = 1; u < 9; ++u)
    if (bidx >= jobs.j[u].blk0) ji = u;
  const TJob jb = jobs.j[ji];
  const int lb = bidx - jb.blk0;
  const int n0 = (lb % jb.nbx) * 32, k0 = (lb / jb.nbx) * 32;
  const int tx = threadIdx.x, ty = threadIdx.y;  // (32,8)
#pragma unroll
  for (int i = 0; i < 4; ++i) {
    const int k = k0 + ty + i * 8, n = n0 + tx;
    tile[ty + i * 8][tx] = (k < jb.K && n < jb.N) ? jb.W[(size_t)k * jb.N + n] : 0.0f;
  }
  __syncthreads();
#pragma unroll
  for (int i = 0; i < 4; ++i) {
    const int n = n0 + ty + i * 8, k = k0 + tx;
    if (n < jb.Npad && k < jb.K) jb.WT[(size_t)n * jb.K + k] = (bf16_t)tile[tx][ty + i * 8];
  }
}

// ---------------- persistent 256x256 GEMM, 2-barrier K-tile schedule ----------------
// Kept for the lm-head: 128^2 tiling measured 3x HBM fetch (1.23GB vs 437MB) and
// regressed 477->605us (round 18) — tile-size traffic beats occupancy here.
// EPI: 0 = bf16 out + bias; 1 = bf16 + bias + gelu; 3 = fp32 out, col<Nout guard
template <int EPI>
__global__ __launch_bounds__(512, 2) void gemm256p(const bf16_t* __restrict__ A,
                                                   const bf16_t* __restrict__ BT,
                                                   const float* __restrict__ bias,
                                                   void* __restrict__ outp,
                                                   int M, int N, int K, int Nout,
                                                   int ntiles) {
  __shared__ __align__(16) char lds[131072];  // A: pi*32K, B: 64K + pi*32K
  const int tid = threadIdx.x;
  const int lane = tid & 63, wave = tid >> 6;
  const int wr = wave >> 2, wc = wave & 3;
  const int fr = lane & 15, fq = lane >> 4;

  const int nmblk = M >> 8;
  const int G = gridDim.x;
  const int flat = blockIdx.x;
  const int xcd = flat & 7, rest = flat >> 3;
  const int q8 = G >> 3, r8 = G & 7;
  const int bid = (xcd < r8 ? xcd * (q8 + 1) : r8 * (q8 + 1) + (xcd - r8) * q8) + rest;
  const int qt = ntiles / G, rt = ntiles % G;
  const int tstart = bid * qt + (bid < rt ? bid : rt);
  const int cnt = qt + (bid < rt ? 1 : 0);
  if (cnt == 0) return;
  const int NT = K >> 6;
  const int sEnd = (tstart + cnt) * NT;

  int srow[4], scb[4];
#pragma unroll
  for (int u = 0; u < 4; ++u) {
    const int s = swz(u * 8192 + tid * 16);
    srow[u] = s >> 7;
    scb[u] = s & 127;
  }
  const char* Abase = (const char*)A;
  const char* Bbase = (const char*)BT;

  auto stageA = [&](int pi, int u, int m0x, int tauK) {
    const char* src = Abase + ((size_t)(m0x + srow[u]) * K + tauK * 64) * 2 + scb[u];
    __builtin_amdgcn_global_load_lds(GLB_AS(src),
        LDS_AS(&lds[pi * 32768 + u * 8192 + wave * 1024]), 16, 0, 0);
  };
  auto stageB = [&](int pi, int u, int n0x, int tauK) {
    const char* src = Bbase + ((size_t)(n0x + srow[u]) * K + tauK * 64) * 2 + scb[u];
    __builtin_amdgcn_global_load_lds(GLB_AS(src),
        LDS_AS(&lds[65536 + pi * 32768 + u * 8192 + wave * 1024]), 16, 0, 0);
  };
  auto rdA = [&](int pi, int msub, int i, int kk) -> f32x4 {
    const int row = wr * 128 + msub * 64 + i * 16 + fr;
    const int off = swz(row * 128 + kk * 64 + fq * 16);
    return *(const f32x4*)(&lds[pi * 32768 + off]);
  };
  auto rdB = [&](int pi, int j, int kk) -> f32x4 {
    const int row = wc * 64 + j * 16 + fr;
    const int off = swz(row * 128 + kk * 64 + fq * 16);
    return *(const f32x4*)(&lds[65536 + pi * 32768 + off]);
  };

  int m0 = (tstart % nmblk) << 8, n0 = (tstart / nmblk) << 8;
  auto adv = [&](int& mx, int& nx, int& tx) {
    if (++tx == NT) { tx = 0; mx += 256; if (mx >= M) { mx = 0; nx += 256; } }
  };

  f32x4 acc[8][4] = {};
  f32x4 a0_[4][2], a1_[4][2], b_[4][2];

  int m2 = m0, n2 = n0, t2 = 0;
  {
#pragma unroll
    for (int u = 0; u < 4; ++u) stageA(0, u, m2, t2);
#pragma unroll
    for (int u = 0; u < 4; ++u) stageB(0, u, n2, t2);
    adv(m2, n2, t2);
#pragma unroll
    for (int u = 0; u < 4; ++u) stageA(1, u, m2, t2);
#pragma unroll
    for (int u = 0; u < 4; ++u) stageB(1, u, n2, t2);
    adv(m2, n2, t2);
  }
  asm volatile("s_waitcnt vmcnt(8)" ::: "memory");
  __builtin_amdgcn_s_barrier();

  int pi = 0;
  int s = tstart * NT;
  for (int t = 0; t < cnt; ++t) {
    for (int tau = 0; tau < NT; ++tau, ++s) {
      const bool h2 = (s + 2 < sEnd);
#pragma unroll
      for (int i = 0; i < 4; ++i) { a0_[i][0] = rdA(pi, 0, i, 0); a0_[i][1] = rdA(pi, 0, i, 1); }
#pragma unroll
      for (int j = 0; j < 2; ++j) { b_[j][0] = rdB(pi, j, 0); b_[j][1] = rdB(pi, j, 1); }
#pragma unroll
      for (int j = 2; j < 4; ++j) { b_[j][0] = rdB(pi, j, 0); b_[j][1] = rdB(pi, j, 1); }
#pragma unroll
      for (int i = 0; i < 4; ++i) { a1_[i][0] = rdA(pi, 1, i, 0); a1_[i][1] = rdA(pi, 1, i, 1); }
      LGKM_WAIT(12);
      __builtin_amdgcn_s_setprio(1);
#pragma unroll
      for (int i = 0; i < 4; ++i)
#pragma unroll
        for (int j = 0; j < 2; ++j) {
          acc[i][j] = mfma16(a0_[i][0], b_[j][0], acc[i][j]);
          acc[i][j] = mfma16(a0_[i][1], b_[j][1], acc[i][j]);
        }
      __builtin_amdgcn_s_setprio(0);
      LGKM_WAIT(8);
      __builtin_amdgcn_s_setprio(1);
#pragma unroll
      for (int i = 0; i < 4; ++i)
#pragma unroll
        for (int j = 0; j < 2; ++j) {
          acc[i][2 + j] = mfma16(a0_[i][0], b_[2 + j][0], acc[i][2 + j]);
          acc[i][2 + j] = mfma16(a0_[i][1], b_[2 + j][1], acc[i][2 + j]);
        }
      __builtin_amdgcn_s_setprio(0);
      LGKM_WAIT(0);
      __builtin_amdgcn_s_barrier();
      if (h2) {
#pragma unroll
        for (int u = 0; u < 4; ++u) stageA(pi, u, m2, t2);
#pragma unroll
        for (int u = 0; u < 4; ++u) stageB(pi, u, n2, t2);
      }
      __builtin_amdgcn_s_setprio(1);
#pragma unroll
      for (int i = 0; i < 4; ++i)
#pragma unroll
        for (int j = 0; j < 2; ++j) {
          acc[4 + i][j] = mfma16(a1_[i][0], b_[j][0], acc[4 + i][j]);
          acc[4 + i][j] = mfma16(a1_[i][1], b_[j][1], acc[4 + i][j]);
        }
#pragma unroll
      for (int i = 0; i < 4; ++i)
#pragma unroll
        for (int j = 0; j < 2; ++j) {
          acc[4 + i][2 + j] = mfma16(a1_[i][0], b_[2 + j][0], acc[4 + i][2 + j]);
          acc[4 + i][2 + j] = mfma16(a1_[i][1], b_[2 + j][1], acc[4 + i][2 + j]);
        }
      __builtin_amdgcn_s_setprio(0);
      // outstanding DMA = 8(s+1) + (h2 ? 8(s+2) : 0); vmcnt(8) valid ONLY when h2.
      if (h2) {
        asm volatile("s_waitcnt vmcnt(8)" ::: "memory");
      } else {
        asm volatile("s_waitcnt vmcnt(0)" ::: "memory");
      }
      __builtin_amdgcn_s_barrier();
      pi ^= 1;
      if (h2) adv(m2, n2, t2);
    }

#pragma unroll
    for (int i8 = 0; i8 < 8; ++i8) {
#pragma unroll
      for (int j4 = 0; j4 < 4; ++j4) {
        const int r0 = m0 + wr * 128 + i8 * 16 + fq * 4;
        const int c = n0 + wc * 64 + j4 * 16 + fr;
        float bv = 0.0f;
        if constexpr (EPI != 3) bv = bias[c];
#pragma unroll
        for (int e = 0; e < 4; ++e) {
          const int r = r0 + e;
          float v = acc[i8][j4][e] + bv;
          if constexpr (EPI == 0) {
            ((bf16_t*)outp)[(size_t)r * N + c] = (bf16_t)v;
          } else if constexpr (EPI == 1) {
            ((bf16_t*)outp)[(size_t)r * N + c] = (bf16_t)gelu_tanh(v);
          } else {
            if (c < Nout) ((float*)outp)[(size_t)r * Nout + c] = v;
          }
        }
      }
    }
#pragma unroll
    for (int i8 = 0; i8 < 8; ++i8)
#pragma unroll
      for (int j4 = 0; j4 < 4; ++j4) acc[i8][j4] = (f32x4){0.0f, 0.0f, 0.0f, 0.0f};
    m0 += 256; if (m0 >= M) { m0 = 0; n0 += 256; }
  }
}

// ---------------- 128x128 pipelined GEMM (3-4 blocks/CU -> cross-block overlap) ----
// EPI: 0 = bf16 out + bias (+ optional fused V-transpose for qkv);
//      1 = bf16 + bias + gelu; 2 = fp32 resid += acc + bias
template <int EPI>
__global__ __launch_bounds__(256) void gemm128p(const bf16_t* __restrict__ A,
                                                const bf16_t* __restrict__ BT,
                                                const float* __restrict__ bias,
                                                void* __restrict__ outp,
                                                int M, int N, int K,
                                                bf16_t* __restrict__ vtp) {
  __shared__ __align__(16) char lds[32768];  // A: pi*8K (128x32), B: 16K + pi*8K
  const int tid = threadIdx.x;
  const int lane = tid & 63, wave = tid >> 6;
  const int wr = wave >> 1, wc = wave & 1;
  const int fr = lane & 15, fq = lane >> 4;

  const int nmblk = M >> 7;
  const int nwg = gridDim.x;
  const int flat = blockIdx.x;
  const int xcd = flat & 7, rest = flat >> 3;
  const int q8 = nwg >> 3, r8 = nwg & 7;
  const int wgid = (xcd < r8 ? xcd * (q8 + 1) : r8 * (q8 + 1) + (xcd - r8) * q8) + rest;
  const int m0 = (wgid % nmblk) * 128;
  const int n0 = (wgid / nmblk) * 128;
  const int NT = K >> 5;

  int srow[2], scb[2];
#pragma unroll
  for (int u = 0; u < 2; ++u) {
    const int s = swz64(u * 4096 + tid * 16);
    srow[u] = s >> 6;
    scb[u] = s & 63;
  }
  const char* Abase = (const char*)A;
  const char* Bbase = (const char*)BT;

  auto stage = [&](int pi, int tauK) {
#pragma unroll
    for (int u = 0; u < 2; ++u) {
      const char* srcA = Abase + ((size_t)(m0 + srow[u]) * K + tauK * 32) * 2 + scb[u];
      __builtin_amdgcn_global_load_lds(GLB_AS(srcA),
          LDS_AS(&lds[pi * 8192 + u * 4096 + wave * 1024]), 16, 0, 0);
      const char* srcB = Bbase + ((size_t)(n0 + srow[u]) * K + tauK * 32) * 2 + scb[u];
      __builtin_amdgcn_global_load_lds(GLB_AS(srcB),
          LDS_AS(&lds[16384 + pi * 8192 + u * 4096 + wave * 1024]), 16, 0, 0);
    }
  };
  auto rdA = [&](int pi, int i) -> f32x4 {
    const int off = swz64((wr * 64 + i * 16 + fr) * 64 + fq * 16);
    return *(const f32x4*)(&lds[pi * 8192 + off]);
  };
  auto rdB = [&](int pi, int j) -> f32x4 {
    const int off = swz64((wc * 64 + j * 16 + fr) * 64 + fq * 16);
    return *(const f32x4*)(&lds[16384 + pi * 8192 + off]);
  };

  f32x4 acc[4][4] = {};

  stage(0, 0); stage(1, 1);
  asm volatile("s_waitcnt vmcnt(4)" ::: "memory");
  __builtin_amdgcn_s_barrier();

  for (int s = 0; s < NT; ++s) {
    const int pi = s & 1;
    f32x4 a_[4], b_[4];
#pragma unroll
    for (int i = 0; i < 4; ++i) a_[i] = rdA(pi, i);
#pragma unroll
    for (int j = 0; j < 4; ++j) b_[j] = rdB(pi, j);
    PHASE_WAIT();
    __builtin_amdgcn_s_setprio(1);
#pragma unroll
    for (int i = 0; i < 4; ++i)
#pragma unroll
      for (int j = 0; j < 4; ++j) acc[i][j] = mfma16(a_[i], b_[j], acc[i][j]);
    __builtin_amdgcn_s_setprio(0);
    __builtin_amdgcn_s_barrier();
    if (s + 2 < NT) {
      stage(pi, s + 2);
      asm volatile("s_waitcnt vmcnt(4)" ::: "memory");
    } else {
      asm volatile("s_waitcnt vmcnt(0)" ::: "memory");
    }
    __builtin_amdgcn_s_barrier();
  }

#pragma unroll
  for (int i = 0; i < 4; ++i) {
#pragma unroll
    for (int j = 0; j < 4; ++j) {
      const int r0 = m0 + wr * 64 + i * 16 + fq * 4;
      const int c = n0 + wc * 64 + j * 16 + fr;
      const float bv = bias[c];
#pragma unroll
      for (int e = 0; e < 4; ++e) {
        const int r = r0 + e;
        float v = acc[i][j][e] + bv;
        if constexpr (EPI == 0) {
          const bf16_t bw = (bf16_t)v;
          ((bf16_t*)outp)[(size_t)r * N + c] = bw;
          // fused V-transpose (qkv only): c in [1536,2304) is the V third.
          if (vtp != nullptr && c >= 1536) {
            const int hd = c - 1536;
            vtp[((size_t)((r >> 10) * 12 + (hd >> 6)) * 64 + (hd & 63)) * 1024 +
                (r & 1023)] = bw;
          }
        } else if constexpr (EPI == 1) {
          ((bf16_t*)outp)[(size_t)r * N + c] = (bf16_t)gelu_tanh(v);
        } else {
          ((float*)outp)[(size_t)r * N + c] += v;
        }
      }
    }
  }
}

// ---------------- MFMA flash attention ----------------
__global__ __launch_bounds__(256) void fattn_k(const bf16_t* __restrict__ qkv,
                                               const bf16_t* __restrict__ vt,
                                               bf16_t* __restrict__ y) {
  __shared__ bf16_t Pl[4][16][40];
  const int wave = threadIdx.x >> 6, lane = threadIdx.x & 63;
  const int wid = blockIdx.x * 4 + wave;
  const int qt = wid & 63;
  const int bh = wid >> 6;
  const int h = bh % 12, b = bh / 12;
  const int fr = lane & 15, fq = lane >> 4;

  const bf16_t* qrow = qkv + (size_t)(b * 1024 + qt * 16 + fr) * 2304 + h * 64;
  const bf16x8 qf0 = *(const bf16x8*)(qrow + fq * 8);
  const bf16x8 qf1 = *(const bf16x8*)(qrow + 32 + fq * 8);

  const bf16_t* kbase = qkv + (size_t)b * 1024 * 2304 + 768 + h * 64 + fq * 8;
  const bf16_t* vbase = vt + ((size_t)bh * 64 + fr) * 1024 + fq * 8;

  f32x4 o[4] = {};
  float mrun[4], lrun[4];
#pragma unroll
  for (int e = 0; e < 4; ++e) { mrun[e] = -1e30f; lrun[e] = 0.0f; }

  const int qg = qt * 16 + fq * 4;
  const int kv_end = qt * 16 + 16;

  for (int kv0 = 0; kv0 < kv_end; kv0 += 32) {
    f32x4 s0 = {}, s1 = {};
    {
      const bf16_t* k0p = kbase + (size_t)(kv0 + fr) * 2304;
      const bf16_t* k1p = kbase + (size_t)(kv0 + 16 + fr) * 2304;
      const bf16x8 kf00 = *(const bf16x8*)(k0p);
      const bf16x8 kf01 = *(const bf16x8*)(k0p + 32);
      const bf16x8 kf10 = *(const bf16x8*)(k1p);
      const bf16x8 kf11 = *(const bf16x8*)(k1p + 32);
      s0 = __builtin_amdgcn_mfma_f32_16x16x32_bf16(qf0, kf00, s0, 0, 0, 0);
      s0 = __builtin_amdgcn_mfma_f32_16x16x32_bf16(qf1, kf01, s0, 0, 0, 0);
      s1 = __builtin_amdgcn_mfma_f32_16x16x32_bf16(qf0, kf10, s1, 0, 0, 0);
      s1 = __builtin_amdgcn_mfma_f32_16x16x32_bf16(qf1, kf11, s1, 0, 0, 0);
    }
    float v0[4], v1[4];
#pragma unroll
    for (int e = 0; e < 4; ++e) {
      v0[e] = (kv0 + fr <= qg + e) ? s0[e] * 0.125f : -1e30f;
      v1[e] = (kv0 + 16 + fr <= qg + e) ? s1[e] * 0.125f : -1e30f;
    }
    float p0[4], p1[4];
#pragma unroll
    for (int e = 0; e < 4; ++e) {
      float mx = fmaxf(v0[e], v1[e]);
      mx = fmaxf(mx, __shfl_xor(mx, 1, 64));
      mx = fmaxf(mx, __shfl_xor(mx, 2, 64));
      mx = fmaxf(mx, __shfl_xor(mx, 4, 64));
      mx = fmaxf(mx, __shfl_xor(mx, 8, 64));
      const float mnew = fmaxf(mrun[e], mx);
      p0[e] = __expf(v0[e] - mnew);
      p1[e] = __expf(v1[e] - mnew);
      float rs = p0[e] + p1[e];
      rs += __shfl_xor(rs, 1, 64);
      rs += __shfl_xor(rs, 2, 64);
      rs += __shfl_xor(rs, 4, 64);
      rs += __shfl_xor(rs, 8, 64);
      const float alpha = __expf(mrun[e] - mnew);
      lrun[e] = lrun[e] * alpha + rs;
      mrun[e] = mnew;
#pragma unroll
      for (int db = 0; db < 4; ++db) o[db][e] *= alpha;
    }
#pragma unroll
    for (int e = 0; e < 4; ++e) {
      Pl[wave][fq * 4 + e][fr] = (bf16_t)p0[e];
      Pl[wave][fq * 4 + e][16 + fr] = (bf16_t)p1[e];
    }
    asm volatile("s_waitcnt lgkmcnt(0)" ::: "memory");
    const bf16x8 pf = *(const bf16x8*)(&Pl[wave][fr][fq * 8]);
#pragma unroll
    for (int db = 0; db < 4; ++db) {
      const bf16x8 vf = *(const bf16x8*)(vbase + (size_t)db * 16 * 1024 + kv0);
      o[db] = __builtin_amdgcn_mfma_f32_16x16x32_bf16(pf, vf, o[db], 0, 0, 0);
    }
  }

#pragma unroll
  for (int db = 0; db < 4; ++db) {
#pragma unroll
    for (int e = 0; e < 4; ++e) {
      const int q = qt * 16 + fq * 4 + e;
      const int d = db * 16 + fr;
      y[(size_t)(b * 1024 + q) * 768 + h * 64 + d] = (bf16_t)(o[db][e] / lrun[e]);
    }
  }
}

// ---------------- host launcher ----------------
extern "C" void kernel_launch(void* const* d_in, const int* in_sizes, int n_in,
                              void* d_out, int out_size, void* d_ws, size_t ws_size,
                              hipStream_t stream) {
  constexpr int Bb = 4, T = 1024, Lg = 2, Vr = 50257, Vp = 50432;
  constexpr int M = Bb * T;

  const int* idx = (const int*)d_in[0];
  const float* wte = (const float*)d_in[2];
  const float* wpe = (const float*)d_in[3];
  const float* ln1_g = (const float*)d_in[4];
  const float* ln1_b = (const float*)d_in[5];
  const float* attn_w = (const float*)d_in[6];
  const float* attn_b = (const float*)d_in[7];
  const float* proj_w = (const float*)d_in[8];
  const float* proj_b = (const float*)d_in[9];
  const float* ln2_g = (const float*)d_in[10];
  const float* ln2_b = (const float*)d_in[11];
  const float* fc_w = (const float*)d_in[12];
  const float* fc_b = (const float*)d_in[13];
  const float* fc2_w = (const float*)d_in[14];
  const float* fc2_b = (const float*)d_in[15];
  const float* lnf_g = (const float*)d_in[16];
  const float* lnf_b = (const float*)d_in[17];
  const float* lm_w = (const float*)d_in[18];
  float* out = (float*)d_out;

  char* wp = (char*)d_ws;
  auto take = [&](size_t n) { char* p = wp; wp += (n + 255) & ~(size_t)255; return p; };
  bf16_t* WqkvT = (bf16_t*)take((size_t)Lg * 2304 * 768 * 2);
  bf16_t* WprojT = (bf16_t*)take((size_t)Lg * 768 * 768 * 2);
  bf16_t* WfcT = (bf16_t*)take((size_t)Lg * 3072 * 768 * 2);
  bf16_t* Wfc2T = (bf16_t*)take((size_t)Lg * 768 * 3072 * 2);
  bf16_t* WlmT = (bf16_t*)take((size_t)Vp * 768 * 2);
  float* xb = (float*)take((size_t)M * 768 * 4);
  bf16_t* hb = (bf16_t*)take((size_t)M * 768 * 2);
  bf16_t* qkvb = (bf16_t*)take((size_t)M * 2304 * 2);
  bf16_t* yb = (bf16_t*)take((size_t)M * 768 * 2);
  bf16_t* actb = (bf16_t*)take((size_t)M * 3072 * 2);
  bf16_t* vtb = (bf16_t*)take((size_t)M * 768 * 2);

  // ---- all weight transposes in one dispatch ----
  TJobs jobs;
  int blk = 0, ji = 0;
  auto addjob = [&](const float* W, bf16_t* WT, int K, int N, int Npad) {
    const int nbx = Npad / 32, nby = K / 32;
    jobs.j[ji++] = TJob{W, WT, K, N, Npad, blk, nbx};
    blk += nbx * nby;
  };
  for (int l = 0; l < Lg; ++l) {
    addjob(attn_w + (size_t)l * 768 * 2304, WqkvT + (size_t)l * 2304 * 768, 768, 2304, 2304);
    addjob(proj_w + (size_t)l * 768 * 768, WprojT + (size_t)l * 768 * 768, 768, 768, 768);
    addjob(fc_w + (size_t)l * 768 * 3072, WfcT + (size_t)l * 3072 * 768, 768, 3072, 3072);
    addjob(fc2_w + (size_t)l * 3072 * 768, Wfc2T + (size_t)l * 768 * 3072, 3072, 768, 768);
  }
  addjob(lm_w, WlmT, 768, Vr, Vp);
  transp_all<<<blk, dim3(32, 8), 0, stream>>>(jobs);

  // ---- fused embed + ln1(l=0) ----
  embed_ln_k<<<M, 256, 0, stream>>>(idx, wte, wpe, ln1_g, ln1_b, xb, hb);

  for (int l = 0; l < Lg; ++l) {
    if (l > 0) ln_k<<<M, 256, 0, stream>>>(xb, ln1_g + l * 768, ln1_b + l * 768, hb);
    // qkv with fused V-transpose into vtb (replaces the vtr_k dispatch)
    gemm128p<0><<<(M / 128) * (2304 / 128), 256, 0, stream>>>(
        hb, WqkvT + (size_t)l * 2304 * 768, attn_b + l * 2304, qkvb, M, 2304, 768, vtb);
    fattn_k<<<(Bb * 12 * 64) / 4, 256, 0, stream>>>(qkvb, vtb, yb);
    gemm128p<2><<<(M / 128) * (768 / 128), 256, 0, stream>>>(
        yb, WprojT + (size_t)l * 768 * 768, proj_b + l * 768, xb, M, 768, 768, nullptr);
    ln_k<<<M, 256, 0, stream>>>(xb, ln2_g + l * 768, ln2_b + l * 768, hb);
    gemm128p<1><<<(M / 128) * (3072 / 128), 256, 0, stream>>>(
        hb, WfcT + (size_t)l * 3072 * 768, fc_b + l * 3072, actb, M, 3072, 768, nullptr);
    gemm128p<2><<<(M / 128) * (768 / 128), 256, 0, stream>>>(
        actb, Wfc2T + (size_t)l * 768 * 3072, fc2_b + l * 768, xb, M, 768, 3072, nullptr);
  }
  ln_k<<<M, 256, 0, stream>>>(xb, lnf_g, lnf_b, hb);
  // lm-head: G=256 (1 block/CU generation; makespan 13 tile-units, prologue
  // amortized over ~12 tiles)
  gemm256p<3><<<256, 512, 0, stream>>>(
      hb, WlmT, nullptr, out, M, Vp, 768, Vr, (M / 256) * (Vp / 256));
}

// Round 22
// 1110.345 us; speedup vs baseline: 1.0294x; 1.0294x over previous
//
#include <hip/hip_runtime.h>
#include <hip/hip_bf16.h>
#include <cstdint>
#include <cstddef>

typedef __bf16 bf16_t;
typedef __bf16 bf16x8 __attribute__((ext_vector_type(8)));
typedef float f32x4 __attribute__((ext_vector_type(4)));

#define GLB_AS(p) ((__attribute__((address_space(1))) void*)(void*)(p))
#define LDS_AS(p) ((__attribute__((address_space(3))) void*)(p))

// ---------------- helpers ----------------
__device__ __forceinline__ float wave_red_sum(float v) {
#pragma unroll
  for (int o = 1; o < 64; o <<= 1) v += __shfl_xor(v, o, 64);
  return v;
}

__device__ __forceinline__ float gelu_tanh(float v) {
  float c = 0.7978845608028654f * (v + 0.044715f * v * v * v);
  return 0.5f * v * (1.0f + tanhf(c));
}

__device__ __forceinline__ f32x4 mfma16(f32x4 a, f32x4 b, f32x4 c) {
  return __builtin_amdgcn_mfma_f32_16x16x32_bf16(
      __builtin_bit_cast(bf16x8, a), __builtin_bit_cast(bf16x8, b), c, 0, 0, 0);
}

// swizzle for 128B-row LDS tiles: XOR row bits (byte bits 7-9) into slot bits 4-6.
__device__ __forceinline__ int swz(int off) { return off ^ ((off >> 3) & 0x70); }
// swizzle for 64B-row LDS tiles.
__device__ __forceinline__ int swz64(int off) { return off ^ ((off >> 3) & 0x30); }

#define PHASE_WAIT()                                    \
  asm volatile("s_waitcnt lgkmcnt(0)" ::: "memory");    \
  __builtin_amdgcn_sched_barrier(0)

#define LGKM_WAIT(N)                                          \
  asm volatile("s_waitcnt lgkmcnt(" #N ")" ::: "memory");     \
  __builtin_amdgcn_sched_barrier(0)

// ---------------- fused embedding + layernorm (layer-0 ln1) ----------------
__global__ __launch_bounds__(256) void embed_ln_k(const int* __restrict__ idx,
                                                  const float* __restrict__ wte,
                                                  const float* __restrict__ wpe,
                                                  const float* __restrict__ g,
                                                  const float* __restrict__ b,
                                                  float* __restrict__ x,
                                                  bf16_t* __restrict__ out) {
  const int m = blockIdx.x;
  const int tid = threadIdx.x;
  const int tok = idx[m];
  const int t = m & 1023;
  float v[3];
#pragma unroll
  for (int i = 0; i < 3; ++i) {
    const int d = tid + i * 256;
    v[i] = wte[(size_t)tok * 768 + d] + wpe[(size_t)t * 768 + d];
    x[(size_t)m * 768 + d] = v[i];
  }
  float s = v[0] + v[1] + v[2];
  float q = v[0] * v[0] + v[1] * v[1] + v[2] * v[2];
  s = wave_red_sum(s);
  q = wave_red_sum(q);
  __shared__ float sm[8];
  const int wave = tid >> 6, lane = tid & 63;
  if (lane == 0) { sm[wave] = s; sm[4 + wave] = q; }
  __syncthreads();
  s = sm[0] + sm[1] + sm[2] + sm[3];
  q = sm[4] + sm[5] + sm[6] + sm[7];
  const float mu = s * (1.0f / 768.0f);
  const float var = q * (1.0f / 768.0f) - mu * mu;
  const float rs = rsqrtf(var + 1e-5f);
  bf16_t* orow = out + (size_t)m * 768;
#pragma unroll
  for (int i = 0; i < 3; ++i) {
    const int d = tid + i * 256;
    orow[d] = (bf16_t)((v[i] - mu) * rs * g[d] + b[d]);
  }
}

// ---------------- layernorm row -> bf16 ----------------
__global__ __launch_bounds__(256) void ln_k(const float* __restrict__ x,
                                            const float* __restrict__ g,
                                            const float* __restrict__ b,
                                            bf16_t* __restrict__ out) {
  const int row = blockIdx.x;
  const int tid = threadIdx.x;
  const float* xr = x + (size_t)row * 768;
  float v0 = xr[tid], v1 = xr[tid + 256], v2 = xr[tid + 512];
  float s = v0 + v1 + v2;
  float q = v0 * v0 + v1 * v1 + v2 * v2;
  s = wave_red_sum(s);
  q = wave_red_sum(q);
  __shared__ float sm[8];
  const int wave = tid >> 6, lane = tid & 63;
  if (lane == 0) { sm[wave] = s; sm[4 + wave] = q; }
  __syncthreads();
  s = sm[0] + sm[1] + sm[2] + sm[3];
  q = sm[4] + sm[5] + sm[6] + sm[7];
  const float mu = s * (1.0f / 768.0f);
  const float var = q * (1.0f / 768.0f) - mu * mu;
  const float rs = rsqrtf(var + 1e-5f);
  bf16_t* orow = out + (size_t)row * 768;
#pragma unroll
  for (int i = 0; i < 3; ++i) {
    const int d = tid + i * 256;
    const float v = (i == 0 ? v0 : (i == 1 ? v1 : v2));
    orow[d] = (bf16_t)((v - mu) * rs * g[d] + b[d]);
  }
}

// ---------------- all weight transposes in ONE dispatch ----------------
struct TJob { const float* W; bf16_t* WT; int K, N, Npad, blk0, nbx; };
struct TJobs { TJob j[9]; };

__global__ __launch_bounds__(256) void transp_all(TJobs jobs) {
  __shared__ float tile[32][33];
  const int bidx = blockIdx.x;
  int ji = 0;
#pragma unroll
  for (int u = 1; u < 9; ++u)
    if (bidx >= jobs.j[u].blk0) ji = u;
  const TJob jb = jobs.j[ji];
  const int lb = bidx - jb.blk0;
  const int n0 = (lb % jb.nbx) * 32, k0 = (lb / jb.nbx) * 32;
  const int tx = threadIdx.x, ty = threadIdx.y;  // (32,8)
#pragma unroll
  for (int i = 0; i < 4; ++i) {
    const int k = k0 + ty + i * 8, n = n0 + tx;
    tile[ty + i * 8][tx] = (k < jb.K && n < jb.N) ? jb.W[(size_t)k * jb.N + n] : 0.0f;
  }
  __syncthreads();
#pragma unroll
  for (int i = 0; i < 4; ++i) {
    const int n = n0 + ty + i * 8, k = k0 + tx;
    if (n < jb.Npad && k < jb.K) jb.WT[(size_t)n * jb.K + k] = (bf16_t)tile[tx][ty + i * 8];
  }
}

// ---------------- V transpose ----------------
__global__ __launch_bounds__(256) void vtr_k(const bf16_t* __restrict__ qkv,
                                             bf16_t* __restrict__ vt) {
  __shared__ bf16_t tile[64][72];
  const int bh = blockIdx.y;
  const int h = bh % 12, b = bh / 12;
  const int t0 = blockIdx.x * 64;
  const int tx = threadIdx.x & 63;
  const int wv = threadIdx.x >> 6;
#pragma unroll
  for (int i = 0; i < 16; ++i) {
    const int r = wv * 16 + i;
    tile[r][tx] = qkv[(size_t)(b * 1024 + t0 + r) * 2304 + 1536 + h * 64 + tx];
  }
  __syncthreads();
#pragma unroll
  for (int i = 0; i < 16; ++i) {
    const int d = wv * 16 + i;
    vt[((size_t)bh * 64 + d) * 1024 + t0 + tx] = tile[tx][d];
  }
}

// ---------------- persistent 256x256 GEMM, 2-barrier K-tile schedule ----------------
// Kept for the lm-head: 128^2 tiling measured 3x HBM fetch (1.23GB vs 437MB) and
// regressed 477->605us (round 18) — tile-size traffic beats occupancy here.
// EPI: 0 = bf16 out + bias; 1 = bf16 + bias + gelu; 3 = fp32 out, col<Nout guard
template <int EPI>
__global__ __launch_bounds__(512, 2) void gemm256p(const bf16_t* __restrict__ A,
                                                   const bf16_t* __restrict__ BT,
                                                   const float* __restrict__ bias,
                                                   void* __restrict__ outp,
                                                   int M, int N, int K, int Nout,
                                                   int ntiles) {
  __shared__ __align__(16) char lds[131072];  // A: pi*32K, B: 64K + pi*32K
  const int tid = threadIdx.x;
  const int lane = tid & 63, wave = tid >> 6;
  const int wr = wave >> 2, wc = wave & 3;
  const int fr = lane & 15, fq = lane >> 4;

  const int nmblk = M >> 8;
  const int G = gridDim.x;
  const int flat = blockIdx.x;
  const int xcd = flat & 7, rest = flat >> 3;
  const int q8 = G >> 3, r8 = G & 7;
  const int bid = (xcd < r8 ? xcd * (q8 + 1) : r8 * (q8 + 1) + (xcd - r8) * q8) + rest;
  const int qt = ntiles / G, rt = ntiles % G;
  const int tstart = bid * qt + (bid < rt ? bid : rt);
  const int cnt = qt + (bid < rt ? 1 : 0);
  if (cnt == 0) return;
  const int NT = K >> 6;
  const int sEnd = (tstart + cnt) * NT;

  int srow[4], scb[4];
#pragma unroll
  for (int u = 0; u < 4; ++u) {
    const int s = swz(u * 8192 + tid * 16);
    srow[u] = s >> 7;
    scb[u] = s & 127;
  }
  const char* Abase = (const char*)A;
  const char* Bbase = (const char*)BT;

  auto stageA = [&](int pi, int u, int m0x, int tauK) {
    const char* src = Abase + ((size_t)(m0x + srow[u]) * K + tauK * 64) * 2 + scb[u];
    __builtin_amdgcn_global_load_lds(GLB_AS(src),
        LDS_AS(&lds[pi * 32768 + u * 8192 + wave * 1024]), 16, 0, 0);
  };
  auto stageB = [&](int pi, int u, int n0x, int tauK) {
    const char* src = Bbase + ((size_t)(n0x + srow[u]) * K + tauK * 64) * 2 + scb[u];
    __builtin_amdgcn_global_load_lds(GLB_AS(src),
        LDS_AS(&lds[65536 + pi * 32768 + u * 8192 + wave * 1024]), 16, 0, 0);
  };
  auto rdA = [&](int pi, int msub, int i, int kk) -> f32x4 {
    const int row = wr * 128 + msub * 64 + i * 16 + fr;
    const int off = swz(row * 128 + kk * 64 + fq * 16);
    return *(const f32x4*)(&lds[pi * 32768 + off]);
  };
  auto rdB = [&](int pi, int j, int kk) -> f32x4 {
    const int row = wc * 64 + j * 16 + fr;
    const int off = swz(row * 128 + kk * 64 + fq * 16);
    return *(const f32x4*)(&lds[65536 + pi * 32768 + off]);
  };

  int m0 = (tstart % nmblk) << 8, n0 = (tstart / nmblk) << 8;
  auto adv = [&](int& mx, int& nx, int& tx) {
    if (++tx == NT) { tx = 0; mx += 256; if (mx >= M) { mx = 0; nx += 256; } }
  };

  f32x4 acc[8][4] = {};
  f32x4 a0_[4][2], a1_[4][2], b_[4][2];

  int m2 = m0, n2 = n0, t2 = 0;
  {
#pragma unroll
    for (int u = 0; u < 4; ++u) stageA(0, u, m2, t2);
#pragma unroll
    for (int u = 0; u < 4; ++u) stageB(0, u, n2, t2);
    adv(m2, n2, t2);
#pragma unroll
    for (int u = 0; u < 4; ++u) stageA(1, u, m2, t2);
#pragma unroll
    for (int u = 0; u < 4; ++u) stageB(1, u, n2, t2);
    adv(m2, n2, t2);
  }
  asm volatile("s_waitcnt vmcnt(8)" ::: "memory");
  __builtin_amdgcn_s_barrier();

  int pi = 0;
  int s = tstart * NT;
  for (int t = 0; t < cnt; ++t) {
    for (int tau = 0; tau < NT; ++tau, ++s) {
      const bool h2 = (s + 2 < sEnd);
#pragma unroll
      for (int i = 0; i < 4; ++i) { a0_[i][0] = rdA(pi, 0, i, 0); a0_[i][1] = rdA(pi, 0, i, 1); }
#pragma unroll
      for (int j = 0; j < 2; ++j) { b_[j][0] = rdB(pi, j, 0); b_[j][1] = rdB(pi, j, 1); }
#pragma unroll
      for (int j = 2; j < 4; ++j) { b_[j][0] = rdB(pi, j, 0); b_[j][1] = rdB(pi, j, 1); }
#pragma unroll
      for (int i = 0; i < 4; ++i) { a1_[i][0] = rdA(pi, 1, i, 0); a1_[i][1] = rdA(pi, 1, i, 1); }
      LGKM_WAIT(12);
      __builtin_amdgcn_s_setprio(1);
#pragma unroll
      for (int i = 0; i < 4; ++i)
#pragma unroll
        for (int j = 0; j < 2; ++j) {
          acc[i][j] = mfma16(a0_[i][0], b_[j][0], acc[i][j]);
          acc[i][j] = mfma16(a0_[i][1], b_[j][1], acc[i][j]);
        }
      __builtin_amdgcn_s_setprio(0);
      LGKM_WAIT(8);
      __builtin_amdgcn_s_setprio(1);
#pragma unroll
      for (int i = 0; i < 4; ++i)
#pragma unroll
        for (int j = 0; j < 2; ++j) {
          acc[i][2 + j] = mfma16(a0_[i][0], b_[2 + j][0], acc[i][2 + j]);
          acc[i][2 + j] = mfma16(a0_[i][1], b_[2 + j][1], acc[i][2 + j]);
        }
      __builtin_amdgcn_s_setprio(0);
      LGKM_WAIT(0);
      __builtin_amdgcn_s_barrier();
      if (h2) {
#pragma unroll
        for (int u = 0; u < 4; ++u) stageA(pi, u, m2, t2);
#pragma unroll
        for (int u = 0; u < 4; ++u) stageB(pi, u, n2, t2);
      }
      __builtin_amdgcn_s_setprio(1);
#pragma unroll
      for (int i = 0; i < 4; ++i)
#pragma unroll
        for (int j = 0; j < 2; ++j) {
          acc[4 + i][j] = mfma16(a1_[i][0], b_[j][0], acc[4 + i][j]);
          acc[4 + i][j] = mfma16(a1_[i][1], b_[j][1], acc[4 + i][j]);
        }
#pragma unroll
      for (int i = 0; i < 4; ++i)
#pragma unroll
        for (int j = 0; j < 2; ++j) {
          acc[4 + i][2 + j] = mfma16(a1_[i][0], b_[2 + j][0], acc[4 + i][2 + j]);
          acc[4 + i][2 + j] = mfma16(a1_[i][1], b_[2 + j][1], acc[4 + i][2 + j]);
        }
      __builtin_amdgcn_s_setprio(0);
      // outstanding DMA = 8(s+1) + (h2 ? 8(s+2) : 0); vmcnt(8) valid ONLY when h2.
      if (h2) {
        asm volatile("s_waitcnt vmcnt(8)" ::: "memory");
      } else {
        asm volatile("s_waitcnt vmcnt(0)" ::: "memory");
      }
      __builtin_amdgcn_s_barrier();
      pi ^= 1;
      if (h2) adv(m2, n2, t2);
    }

#pragma unroll
    for (int i8 = 0; i8 < 8; ++i8) {
#pragma unroll
      for (int j4 = 0; j4 < 4; ++j4) {
        const int r0 = m0 + wr * 128 + i8 * 16 + fq * 4;
        const int c = n0 + wc * 64 + j4 * 16 + fr;
        float bv = 0.0f;
        if constexpr (EPI != 3) bv = bias[c];
#pragma unroll
        for (int e = 0; e < 4; ++e) {
          const int r = r0 + e;
          float v = acc[i8][j4][e] + bv;
          if constexpr (EPI == 0) {
            ((bf16_t*)outp)[(size_t)r * N + c] = (bf16_t)v;
          } else if constexpr (EPI == 1) {
            ((bf16_t*)outp)[(size_t)r * N + c] = (bf16_t)gelu_tanh(v);
          } else {
            if (c < Nout) ((float*)outp)[(size_t)r * Nout + c] = v;
          }
        }
      }
    }
#pragma unroll
    for (int i8 = 0; i8 < 8; ++i8)
#pragma unroll
      for (int j4 = 0; j4 < 4; ++j4) acc[i8][j4] = (f32x4){0.0f, 0.0f, 0.0f, 0.0f};
    m0 += 256; if (m0 >= M) { m0 = 0; n0 += 256; }
  }
}

// ---------------- 128x128 pipelined GEMM (3-4 blocks/CU -> cross-block overlap) ----
// EPI: 0 = bf16 out + bias; 1 = bf16 + bias + gelu; 2 = fp32 resid += acc + bias
template <int EPI>
__global__ __launch_bounds__(256) void gemm128p(const bf16_t* __restrict__ A,
                                                const bf16_t* __restrict__ BT,
                                                const float* __restrict__ bias,
                                                void* __restrict__ outp,
                                                int M, int N, int K) {
  __shared__ __align__(16) char lds[32768];  // A: pi*8K (128x32), B: 16K + pi*8K
  const int tid = threadIdx.x;
  const int lane = tid & 63, wave = tid >> 6;
  const int wr = wave >> 1, wc = wave & 1;
  const int fr = lane & 15, fq = lane >> 4;

  const int nmblk = M >> 7;
  const int nwg = gridDim.x;
  const int flat = blockIdx.x;
  const int xcd = flat & 7, rest = flat >> 3;
  const int q8 = nwg >> 3, r8 = nwg & 7;
  const int wgid = (xcd < r8 ? xcd * (q8 + 1) : r8 * (q8 + 1) + (xcd - r8) * q8) + rest;
  const int m0 = (wgid % nmblk) * 128;
  const int n0 = (wgid / nmblk) * 128;
  const int NT = K >> 5;

  int srow[2], scb[2];
#pragma unroll
  for (int u = 0; u < 2; ++u) {
    const int s = swz64(u * 4096 + tid * 16);
    srow[u] = s >> 6;
    scb[u] = s & 63;
  }
  const char* Abase = (const char*)A;
  const char* Bbase = (const char*)BT;

  auto stage = [&](int pi, int tauK) {
#pragma unroll
    for (int u = 0; u < 2; ++u) {
      const char* srcA = Abase + ((size_t)(m0 + srow[u]) * K + tauK * 32) * 2 + scb[u];
      __builtin_amdgcn_global_load_lds(GLB_AS(srcA),
          LDS_AS(&lds[pi * 8192 + u * 4096 + wave * 1024]), 16, 0, 0);
      const char* srcB = Bbase + ((size_t)(n0 + srow[u]) * K + tauK * 32) * 2 + scb[u];
      __builtin_amdgcn_global_load_lds(GLB_AS(srcB),
          LDS_AS(&lds[16384 + pi * 8192 + u * 4096 + wave * 1024]), 16, 0, 0);
    }
  };
  auto rdA = [&](int pi, int i) -> f32x4 {
    const int off = swz64((wr * 64 + i * 16 + fr) * 64 + fq * 16);
    return *(const f32x4*)(&lds[pi * 8192 + off]);
  };
  auto rdB = [&](int pi, int j) -> f32x4 {
    const int off = swz64((wc * 64 + j * 16 + fr) * 64 + fq * 16);
    return *(const f32x4*)(&lds[16384 + pi * 8192 + off]);
  };

  f32x4 acc[4][4] = {};

  stage(0, 0); stage(1, 1);
  asm volatile("s_waitcnt vmcnt(4)" ::: "memory");
  __builtin_amdgcn_s_barrier();

  for (int s = 0; s < NT; ++s) {
    const int pi = s & 1;
    f32x4 a_[4], b_[4];
#pragma unroll
    for (int i = 0; i < 4; ++i) a_[i] = rdA(pi, i);
#pragma unroll
    for (int j = 0; j < 4; ++j) b_[j] = rdB(pi, j);
    PHASE_WAIT();
    __builtin_amdgcn_s_setprio(1);
#pragma unroll
    for (int i = 0; i < 4; ++i)
#pragma unroll
      for (int j = 0; j < 4; ++j) acc[i][j] = mfma16(a_[i], b_[j], acc[i][j]);
    __builtin_amdgcn_s_setprio(0);
    __builtin_amdgcn_s_barrier();
    if (s + 2 < NT) {
      stage(pi, s + 2);
      asm volatile("s_waitcnt vmcnt(4)" ::: "memory");
    } else {
      asm volatile("s_waitcnt vmcnt(0)" ::: "memory");
    }
    __builtin_amdgcn_s_barrier();
  }

#pragma unroll
  for (int i = 0; i < 4; ++i) {
#pragma unroll
    for (int j = 0; j < 4; ++j) {
      const int r0 = m0 + wr * 64 + i * 16 + fq * 4;
      const int c = n0 + wc * 64 + j * 16 + fr;
      const float bv = bias[c];
#pragma unroll
      for (int e = 0; e < 4; ++e) {
        const int r = r0 + e;
        float v = acc[i][j][e] + bv;
        if constexpr (EPI == 0) {
          ((bf16_t*)outp)[(size_t)r * N + c] = (bf16_t)v;
        } else if constexpr (EPI == 1) {
          ((bf16_t*)outp)[(size_t)r * N + c] = (bf16_t)gelu_tanh(v);
        } else {
          ((float*)outp)[(size_t)r * N + c] += v;
        }
      }
    }
  }
}

// ---------------- MFMA flash attention ----------------
__global__ __launch_bounds__(256) void fattn_k(const bf16_t* __restrict__ qkv,
                                               const bf16_t* __restrict__ vt,
                                               bf16_t* __restrict__ y) {
  __shared__ bf16_t Pl[4][16][40];
  const int wave = threadIdx.x >> 6, lane = threadIdx.x & 63;
  const int wid = blockIdx.x * 4 + wave;
  const int qt = wid & 63;
  const int bh = wid >> 6;
  const int h = bh % 12, b = bh / 12;
  const int fr = lane & 15, fq = lane >> 4;

  const bf16_t* qrow = qkv + (size_t)(b * 1024 + qt * 16 + fr) * 2304 + h * 64;
  const bf16x8 qf0 = *(const bf16x8*)(qrow + fq * 8);
  const bf16x8 qf1 = *(const bf16x8*)(qrow + 32 + fq * 8);

  const bf16_t* kbase = qkv + (size_t)b * 1024 * 2304 + 768 + h * 64 + fq * 8;
  const bf16_t* vbase = vt + ((size_t)bh * 64 + fr) * 1024 + fq * 8;

  f32x4 o[4] = {};
  float mrun[4], lrun[4];
#pragma unroll
  for (int e = 0; e < 4; ++e) { mrun[e] = -1e30f; lrun[e] = 0.0f; }

  const int qg = qt * 16 + fq * 4;
  const int kv_end = qt * 16 + 16;

  for (int kv0 = 0; kv0 < kv_end; kv0 += 32) {
    f32x4 s0 = {}, s1 = {};
    {
      const bf16_t* k0p = kbase + (size_t)(kv0 + fr) * 2304;
      const bf16_t* k1p = kbase + (size_t)(kv0 + 16 + fr) * 2304;
      const bf16x8 kf00 = *(const bf16x8*)(k0p);
      const bf16x8 kf01 = *(const bf16x8*)(k0p + 32);
      const bf16x8 kf10 = *(const bf16x8*)(k1p);
      const bf16x8 kf11 = *(const bf16x8*)(k1p + 32);
      s0 = __builtin_amdgcn_mfma_f32_16x16x32_bf16(qf0, kf00, s0, 0, 0, 0);
      s0 = __builtin_amdgcn_mfma_f32_16x16x32_bf16(qf1, kf01, s0, 0, 0, 0);
      s1 = __builtin_amdgcn_mfma_f32_16x16x32_bf16(qf0, kf10, s1, 0, 0, 0);
      s1 = __builtin_amdgcn_mfma_f32_16x16x32_bf16(qf1, kf11, s1, 0, 0, 0);
    }
    float v0[4], v1[4];
#pragma unroll
    for (int e = 0; e < 4; ++e) {
      v0[e] = (kv0 + fr <= qg + e) ? s0[e] * 0.125f : -1e30f;
      v1[e] = (kv0 + 16 + fr <= qg + e) ? s1[e] * 0.125f : -1e30f;
    }
    float p0[4], p1[4];
#pragma unroll
    for (int e = 0; e < 4; ++e) {
      float mx = fmaxf(v0[e], v1[e]);
      mx = fmaxf(mx, __shfl_xor(mx, 1, 64));
      mx = fmaxf(mx, __shfl_xor(mx, 2, 64));
      mx = fmaxf(mx, __shfl_xor(mx, 4, 64));
      mx = fmaxf(mx, __shfl_xor(mx, 8, 64));
      const float mnew = fmaxf(mrun[e], mx);
      p0[e] = __expf(v0[e] - mnew);
      p1[e] = __expf(v1[e] - mnew);
      float rs = p0[e] + p1[e];
      rs += __shfl_xor(rs, 1, 64);
      rs += __shfl_xor(rs, 2, 64);
      rs += __shfl_xor(rs, 4, 64);
      rs += __shfl_xor(rs, 8, 64);
      const float alpha = __expf(mrun[e] - mnew);
      lrun[e] = lrun[e] * alpha + rs;
      mrun[e] = mnew;
#pragma unroll
      for (int db = 0; db < 4; ++db) o[db][e] *= alpha;
    }
#pragma unroll
    for (int e = 0; e < 4; ++e) {
      Pl[wave][fq * 4 + e][fr] = (bf16_t)p0[e];
      Pl[wave][fq * 4 + e][16 + fr] = (bf16_t)p1[e];
    }
    asm volatile("s_waitcnt lgkmcnt(0)" ::: "memory");
    const bf16x8 pf = *(const bf16x8*)(&Pl[wave][fr][fq * 8]);
#pragma unroll
    for (int db = 0; db < 4; ++db) {
      const bf16x8 vf = *(const bf16x8*)(vbase + (size_t)db * 16 * 1024 + kv0);
      o[db] = __builtin_amdgcn_mfma_f32_16x16x32_bf16(pf, vf, o[db], 0, 0, 0);
    }
  }

#pragma unroll
  for (int db = 0; db < 4; ++db) {
#pragma unroll
    for (int e = 0; e < 4; ++e) {
      const int q = qt * 16 + fq * 4 + e;
      const int d = db * 16 + fr;
      y[(size_t)(b * 1024 + q) * 768 + h * 64 + d] = (bf16_t)(o[db][e] / lrun[e]);
    }
  }
}

// ---------------- host launcher ----------------
extern "C" void kernel_launch(void* const* d_in, const int* in_sizes, int n_in,
                              void* d_out, int out_size, void* d_ws, size_t ws_size,
                              hipStream_t stream) {
  constexpr int Bb = 4, T = 1024, Lg = 2, Vr = 50257, Vp = 50432;
  constexpr int M = Bb * T;

  const int* idx = (const int*)d_in[0];
  const float* wte = (const float*)d_in[2];
  const float* wpe = (const float*)d_in[3];
  const float* ln1_g = (const float*)d_in[4];
  const float* ln1_b = (const float*)d_in[5];
  const float* attn_w = (const float*)d_in[6];
  const float* attn_b = (const float*)d_in[7];
  const float* proj_w = (const float*)d_in[8];
  const float* proj_b = (const float*)d_in[9];
  const float* ln2_g = (const float*)d_in[10];
  const float* ln2_b = (const float*)d_in[11];
  const float* fc_w = (const float*)d_in[12];
  const float* fc_b = (const float*)d_in[13];
  const float* fc2_w = (const float*)d_in[14];
  const float* fc2_b = (const float*)d_in[15];
  const float* lnf_g = (const float*)d_in[16];
  const float* lnf_b = (const float*)d_in[17];
  const float* lm_w = (const float*)d_in[18];
  float* out = (float*)d_out;

  char* wp = (char*)d_ws;
  auto take = [&](size_t n) { char* p = wp; wp += (n + 255) & ~(size_t)255; return p; };
  bf16_t* WqkvT = (bf16_t*)take((size_t)Lg * 2304 * 768 * 2);
  bf16_t* WprojT = (bf16_t*)take((size_t)Lg * 768 * 768 * 2);
  bf16_t* WfcT = (bf16_t*)take((size_t)Lg * 3072 * 768 * 2);
  bf16_t* Wfc2T = (bf16_t*)take((size_t)Lg * 768 * 3072 * 2);
  bf16_t* WlmT = (bf16_t*)take((size_t)Vp * 768 * 2);
  float* xb = (float*)take((size_t)M * 768 * 4);
  bf16_t* hb = (bf16_t*)take((size_t)M * 768 * 2);
  bf16_t* qkvb = (bf16_t*)take((size_t)M * 2304 * 2);
  bf16_t* yb = (bf16_t*)take((size_t)M * 768 * 2);
  bf16_t* actb = (bf16_t*)take((size_t)M * 3072 * 2);
  bf16_t* vtb = (bf16_t*)take((size_t)M * 768 * 2);

  // ---- all weight transposes in one dispatch ----
  TJobs jobs;
  int blk = 0, ji = 0;
  auto addjob = [&](const float* W, bf16_t* WT, int K, int N, int Npad) {
    const int nbx = Npad / 32, nby = K / 32;
    jobs.j[ji++] = TJob{W, WT, K, N, Npad, blk, nbx};
    blk += nbx * nby;
  };
  for (int l = 0; l < Lg; ++l) {
    addjob(attn_w + (size_t)l * 768 * 2304, WqkvT + (size_t)l * 2304 * 768, 768, 2304, 2304);
    addjob(proj_w + (size_t)l * 768 * 768, WprojT + (size_t)l * 768 * 768, 768, 768, 768);
    addjob(fc_w + (size_t)l * 768 * 3072, WfcT + (size_t)l * 3072 * 768, 768, 3072, 3072);
    addjob(fc2_w + (size_t)l * 3072 * 768, Wfc2T + (size_t)l * 768 * 3072, 3072, 768, 768);
  }
  addjob(lm_w, WlmT, 768, Vr, Vp);
  transp_all<<<blk, dim3(32, 8), 0, stream>>>(jobs);

  // ---- fused embed + ln1(l=0) ----
  embed_ln_k<<<M, 256, 0, stream>>>(idx, wte, wpe, ln1_g, ln1_b, xb, hb);

  for (int l = 0; l < Lg; ++l) {
    if (l > 0) ln_k<<<M, 256, 0, stream>>>(xb, ln1_g + l * 768, ln1_b + l * 768, hb);
    gemm128p<0><<<(M / 128) * (2304 / 128), 256, 0, stream>>>(
        hb, WqkvT + (size_t)l * 2304 * 768, attn_b + l * 2304, qkvb, M, 2304, 768);
    vtr_k<<<dim3(T / 64, Bb * 12), 256, 0, stream>>>(qkvb, vtb);
    fattn_k<<<(Bb * 12 * 64) / 4, 256, 0, stream>>>(qkvb, vtb, yb);
    gemm128p<2><<<(M / 128) * (768 / 128), 256, 0, stream>>>(
        yb, WprojT + (size_t)l * 768 * 768, proj_b + l * 768, xb, M, 768, 768);
    ln_k<<<M, 256, 0, stream>>>(xb, ln2_g + l * 768, ln2_b + l * 768, hb);
    gemm128p<1><<<(M / 128) * (3072 / 128), 256, 0, stream>>>(
        hb, WfcT + (size_t)l * 3072 * 768, fc_b + l * 3072, actb, M, 3072, 768);
    gemm128p<2><<<(M / 128) * (768 / 128), 256, 0, stream>>>(
        actb, Wfc2T + (size_t)l * 768 * 3072, fc2_b + l * 768, xb, M, 768, 3072);
  }
  ln_k<<<M, 256, 0, stream>>>(xb, lnf_g, lnf_b, hb);
  // lm-head: G=256 (1 block/CU generation; makespan 13 tile-units, prologue
  // amortized over ~12 tiles)
  gemm256p<3><<<256, 512, 0, stream>>>(
      hb, WlmT, nullptr, out, M, Vp, 768, Vr, (M / 256) * (Vp / 256));
}